// Round 4
// baseline (710.438 us; speedup 1.0000x reference)
//
#include <hip/hip_runtime.h>
#include <hip/hip_bf16.h>
#include <math.h>

#define TSEQ 2048
#define DIN  32
#define HID  20
#define G4   80
#define TILE 16
#define NT   (TSEQ / TILE)
#define L2E  1.44269504088896340736f

#if __has_builtin(__builtin_amdgcn_exp2f)
#define EXP2(x) __builtin_amdgcn_exp2f(x)
#else
#define EXP2(x) __expf((x) * 0.69314718055994531f)
#endif

__device__ __forceinline__ float rl(float v, int l) {
    return __int_as_float(__builtin_amdgcn_readlane(__float_as_int(v), l));
}

// sigmoid with pre-scaled (x*log2e) argument: 1/(1+2^-xs)
__device__ __forceinline__ float sig2(float xs) {
    return __builtin_amdgcn_rcpf(1.0f + EXP2(-xs));
}

// cross-half (lane ^ 32) exchange via v_permlane32_swap, direction-agnostic:
// after swap(a=v, b=v), one of {a,b} holds the low-half broadcast, the other
// the high-half broadcast (we don't rely on which): a+b-v = opposite half.
__device__ __forceinline__ float xhalf(float v) {
    float a = v, b = v;
    asm("v_permlane32_swap_b32 %0, %1" : "+v"(a), "+v"(b));
    return (a + b) - v;
}

__device__ __forceinline__ float samp(const float* mu, const float* rho,
                                      const float* eps, int i) {
    return mu[i] + log1pf(__expf(rho[i])) * eps[i];
}

__global__ __launch_bounds__(128, 1) void blstm_kernel(
    const float* __restrict__ x,
    const float* __restrict__ wih_mu, const float* __restrict__ wih_rho, const float* __restrict__ wih_eps,
    const float* __restrict__ whh_mu, const float* __restrict__ whh_rho, const float* __restrict__ whh_eps,
    const float* __restrict__ bmu,    const float* __restrict__ brho,    const float* __restrict__ beps,
    const float* __restrict__ wlin,   const float* __restrict__ blin,
    float* __restrict__ out)
{
    __shared__ __align__(16) float lds_xg[2][TILE * G4];  // double-buffered xg tiles (permuted)
    __shared__ __align__(16) float hist[64 * HID];        // h ring for output flush

    const int tid  = threadIdx.x;
    const int lane = tid & 63;
    const int b    = blockIdx.x;
    const float* xrow = x + (size_t)b * TSEQ * DIN;
    float* outp = out + (size_t)b * TSEQ;

    if (tid < 64) {
        // ======================= CONSUMER (recurrence) =======================
        const int p  = lane >> 5;                  // 0: (i,f) cols; 1: (g,o) cols
        const int k  = lane & 31;
        const int ke = (k < HID) ? k : (HID - 1);  // junk lanes mirror unit 19
        const int g1 = p * 40 + ke;                // i_k or g_k
        const int g2 = g1 + HID;                   // f_k or o_k
        const float aAct = p ? 2.0f : 1.0f;        // tanh(x)=2*sig(2x)-1 on upper half
        const float cAct = 1.0f - aAct;
        const float sc1 = aAct * L2E;              // exp2-domain scales folded into weights
        const float sc2 = L2E;

        float w1[HID], w2[HID];
#pragma unroll
        for (int j = 0; j < HID; ++j) {
            w1[j] = samp(whh_mu, whh_rho, whh_eps, j * G4 + g1) * sc1;
            w2[j] = samp(whh_mu, whh_rho, whh_eps, j * G4 + g2) * sc2;
        }
        const int coff = p * 40 + ke * 2;          // float2 slot in permuted xg row

        float h = 0.0f, c = 0.0f;
        for (int kt = 0; kt < NT; ++kt) {
            __syncthreads();                       // tile kt ready
            const float* xg = lds_xg[kt & 1];
            float2 xgr[TILE];
#pragma unroll
            for (int r = 0; r < TILE; ++r)
                xgr[r] = *(const float2*)&xg[r * G4 + coff];

#pragma unroll
            for (int ti = 0; ti < TILE; ++ti) {
                // --- broadcast h into SGPRs as a burst, then fence the schedule
                // so no dependent FMA is interleaved into the readlane stream
                // (readlane->SGPR-read hazard wait-states).
                float hj[HID];
#pragma unroll
                for (int j = 0; j < HID; ++j) hj[j] = rl(h, j);
                __builtin_amdgcn_sched_barrier(0);

                float d1a = xgr[ti].x, d2a = xgr[ti].y;
                float d1b = 0.0f, d2b = 0.0f;
#pragma unroll
                for (int j = 0; j < HID; j += 2) {
                    d1a = fmaf(hj[j],     w1[j],     d1a);
                    d2a = fmaf(hj[j],     w2[j],     d2a);
                    d1b = fmaf(hj[j + 1], w1[j + 1], d1b);
                    d2b = fmaf(hj[j + 1], w2[j + 1], d2b);
                }
                const float d1 = d1a + d1b;
                const float d2 = d2a + d2b;

                const float s1   = sig2(d1);               // sig(i) or sig(2g)
                const float act1 = fmaf(s1, aAct, cAct);   // sig(i) or tanh(g)
                const float act2 = sig2(d2);               // sig(f) or sig(o)

                const float og1 = xhalf(act1);             // low lanes: tanh(g)
                const float og2 = xhalf(act2);             // low lanes: sig(o)

                c = fmaf(act2, c, act1 * og1);             // low: f*c + i*tanh(g)
                const float tc = fmaf(2.0f, sig2(c * (2.0f * L2E)), -1.0f); // tanh(c)
                h = og2 * tc;                              // low: o * tanh(c)

                const int t = kt * TILE + ti;
                if (lane < HID) hist[(t & 63) * HID + lane] = h;
            }
        }
        __syncthreads();                           // expose last tile's hist
    } else {
        // ======================= PRODUCER (xg + output) =======================
        const int cA = lane;                       // columns 0..63
        const int cB = 64 + (lane & 15);           // columns 64..79 ('o' tail)
        const float scA = ((cA >= 40 && cA < 60) ? 2.0f : 1.0f) * L2E;
        const float scB = L2E;

        float wA[DIN], wB[DIN];
#pragma unroll
        for (int d = 0; d < DIN; ++d) {
            wA[d] = samp(wih_mu, wih_rho, wih_eps, d * G4 + cA) * scA;
            wB[d] = samp(wih_mu, wih_rho, wih_eps, d * G4 + cB) * scB;
        }
        const float biasA = samp(bmu, brho, beps, cA) * scA;
        const float biasB = samp(bmu, brho, beps, cB) * scB;

        const int posA = ((cA >= 40) ? 40 : 0) + (cA % 20) * 2 + ((cA / 20) & 1);
        const int posB = ((cB >= 40) ? 40 : 0) + (cB % 20) * 2 + ((cB / 20) & 1);
        const int qs   = (lane >> 4) * 4;          // dotB step group

        float wl[HID];
#pragma unroll
        for (int j = 0; j < HID; ++j) wl[j] = wlin[j];
        const float bl = blin[0];

        // produce tile kt into lds_xg[kt&1]
        auto produce = [&](int kt) {
            const float* xu = xrow + kt * TILE * DIN;
            float* xgb = lds_xg[kt & 1];
            // dotA: uniform x (scalarizable s_loads), 16 steps, 64 columns
#pragma unroll
            for (int s = 0; s < TILE; ++s) {
                float a0 = 0.0f, a1 = 0.0f;
#pragma unroll
                for (int d = 0; d < 16; ++d) {
                    a0 = fmaf(xu[s * DIN + d],      wA[d],      a0);
                    a1 = fmaf(xu[s * DIN + d + 16], wA[d + 16], a1);
                }
                xgb[s * G4 + posA] = biasA + a0 + a1;
            }
            // dotB: 16 extra columns, 4 steps per lane-group, x direct from
            // global (16-lane broadcast addresses, L1-resident 2KB tile) —
            // replaces the 4-way bank-conflicted lds_x path.
#pragma unroll
            for (int jj = 0; jj < 4; ++jj) {
                const int s = qs + jj;
                const float* xs = xu + s * DIN;
                float b0 = 0.0f, b1 = 0.0f;
#pragma unroll
                for (int d = 0; d < 16; ++d) {
                    b0 = fmaf(xs[d],      wB[d],      b0);
                    b1 = fmaf(xs[d + 16], wB[d + 16], b1);
                }
                xgb[s * G4 + posB] = biasB + b0 + b1;
            }
        };

        // flush outputs for tile ft (hist already complete & barrier-visible)
        auto flush = [&](int ft) {
            if (lane < TILE) {
                const int t = ft * TILE + lane;
                const float4* hr = (const float4*)&hist[(t & 63) * HID];
                const float4 r0 = hr[0], r1 = hr[1], r2 = hr[2], r3 = hr[3], r4 = hr[4];
                float acc = bl;
                acc = fmaf(r0.x, wl[0],  acc); acc = fmaf(r0.y, wl[1],  acc);
                acc = fmaf(r0.z, wl[2],  acc); acc = fmaf(r0.w, wl[3],  acc);
                acc = fmaf(r1.x, wl[4],  acc); acc = fmaf(r1.y, wl[5],  acc);
                acc = fmaf(r1.z, wl[6],  acc); acc = fmaf(r1.w, wl[7],  acc);
                acc = fmaf(r2.x, wl[8],  acc); acc = fmaf(r2.y, wl[9],  acc);
                acc = fmaf(r2.z, wl[10], acc); acc = fmaf(r2.w, wl[11], acc);
                acc = fmaf(r3.x, wl[12], acc); acc = fmaf(r3.y, wl[13], acc);
                acc = fmaf(r3.z, wl[14], acc); acc = fmaf(r3.w, wl[15], acc);
                acc = fmaf(r4.x, wl[16], acc); acc = fmaf(r4.y, wl[17], acc);
                acc = fmaf(r4.z, wl[18], acc); acc = fmaf(r4.w, wl[19], acc);
                outp[t] = acc;
            }
        };

        produce(0);
        for (int kt = 0; kt < NT; ++kt) {
            __syncthreads();                       // release tile kt
            if (kt + 1 < NT) produce(kt + 1);
            if (kt >= 1)     flush(kt - 1);
        }
        __syncthreads();                           // consumer's last tile visible
        flush(NT - 1);
    }
}

extern "C" void kernel_launch(void* const* d_in, const int* in_sizes, int n_in,
                              void* d_out, int out_size, void* d_ws, size_t ws_size,
                              hipStream_t stream) {
    const float* x       = (const float*)d_in[0];
    const float* wih_mu  = (const float*)d_in[1];
    const float* wih_rho = (const float*)d_in[2];
    const float* wih_eps = (const float*)d_in[3];
    const float* whh_mu  = (const float*)d_in[4];
    const float* whh_rho = (const float*)d_in[5];
    const float* whh_eps = (const float*)d_in[6];
    const float* bmu     = (const float*)d_in[7];
    const float* brho    = (const float*)d_in[8];
    const float* beps    = (const float*)d_in[9];
    const float* wlin    = (const float*)d_in[10];
    const float* blin    = (const float*)d_in[11];
    float* out = (float*)d_out;

    const int B = in_sizes[0] / (TSEQ * DIN);   // 256

    blstm_kernel<<<B, 128, 0, stream>>>(x, wih_mu, wih_rho, wih_eps,
                                        whh_mu, whh_rho, whh_eps,
                                        bmu, brho, beps, wlin, blin, out);
}

// Round 7
// 407.657 us; speedup vs baseline: 1.7427x; 1.7427x over previous
//
#include <hip/hip_runtime.h>
#include <hip/hip_bf16.h>
#include <math.h>

#define TSEQ 2048
#define DIN  32
#define HID  20
#define G4   80
#define TILE 16
#define NT   (TSEQ / TILE)
#define L2E  1.44269504088896340736f

#if __has_builtin(__builtin_amdgcn_exp2f)
#define EXP2(x) __builtin_amdgcn_exp2f(x)
#else
#define EXP2(x) __expf((x) * 0.69314718055994531f)
#endif

__device__ __forceinline__ float rl(float v, int l) {
    return __int_as_float(__builtin_amdgcn_readlane(__float_as_int(v), l));
}

// sigmoid with pre-scaled (x*log2e) argument: 1/(1+2^-xs)
__device__ __forceinline__ float sig2(float xs) {
    return __builtin_amdgcn_rcpf(1.0f + EXP2(-xs));
}

// cross-half (lane ^ 32) exchange via v_permlane32_swap, direction-agnostic:
// after swap(a=v, b=v), one of {a,b} holds the low-half broadcast, the other
// the high-half broadcast (we don't rely on which): a+b-v = opposite half.
__device__ __forceinline__ float xhalf(float v) {
    float a = v, b = v;
    asm("v_permlane32_swap_b32 %0, %1" : "+v"(a), "+v"(b));
    return (a + b) - v;
}

__device__ __forceinline__ float samp(const float* mu, const float* rho,
                                      const float* eps, int i) {
    return mu[i] + log1pf(__expf(rho[i])) * eps[i];
}

__global__ __launch_bounds__(128, 1) void blstm_kernel(
    const float* __restrict__ x,
    const float* __restrict__ wih_mu, const float* __restrict__ wih_rho, const float* __restrict__ wih_eps,
    const float* __restrict__ whh_mu, const float* __restrict__ whh_rho, const float* __restrict__ whh_eps,
    const float* __restrict__ bmu,    const float* __restrict__ brho,    const float* __restrict__ beps,
    const float* __restrict__ wlin,   const float* __restrict__ blin,
    float* __restrict__ out)
{
    __shared__ __align__(16) float lds_xg[2][TILE * G4];  // double-buffered xg tiles (permuted)
    __shared__ __align__(16) float lds_x[TILE * DIN];     // producer-private x stage
    __shared__ __align__(16) float hist[64 * HID];        // h ring for output flush

    const int tid  = threadIdx.x;
    const int lane = tid & 63;
    const int b    = blockIdx.x;
    const float* xrow = x + (size_t)b * TSEQ * DIN;
    float* outp = out + (size_t)b * TSEQ;

    if (tid < 64) {
        // ======================= CONSUMER (recurrence) =======================
        // (R2 consumer + R4-proven burst-readlane / sched_barrier)
        const int p  = lane >> 5;                  // 0: (i,f) cols; 1: (g,o) cols
        const int k  = lane & 31;
        const int ke = (k < HID) ? k : (HID - 1);  // junk lanes mirror unit 19
        const int g1 = p * 40 + ke;                // i_k or g_k
        const int g2 = g1 + HID;                   // f_k or o_k
        const float aAct = p ? 2.0f : 1.0f;        // tanh(x)=2*sig(2x)-1 on upper half
        const float cAct = 1.0f - aAct;
        const float sc1 = aAct * L2E;              // exp2-domain scales folded into weights
        const float sc2 = L2E;

        float w1[HID], w2[HID];
#pragma unroll
        for (int j = 0; j < HID; ++j) {
            w1[j] = samp(whh_mu, whh_rho, whh_eps, j * G4 + g1) * sc1;
            w2[j] = samp(whh_mu, whh_rho, whh_eps, j * G4 + g2) * sc2;
        }
        const int coff = p * 40 + ke * 2;          // float2 slot in permuted xg row

        float h = 0.0f, c = 0.0f;
        for (int kt = 0; kt < NT; ++kt) {
            __syncthreads();                       // tile kt ready
            const float* xg = lds_xg[kt & 1];
            float2 xgr[TILE];
#pragma unroll
            for (int r = 0; r < TILE; ++r)
                xgr[r] = *(const float2*)&xg[r * G4 + coff];

#pragma unroll
            for (int ti = 0; ti < TILE; ++ti) {
                // burst-broadcast h into SGPRs, then fence the scheduler so no
                // dependent FMA interleaves into the readlane stream
                // (readlane->SGPR-read hazard wait-states). Proven in R4.
                float hj[HID];
#pragma unroll
                for (int j = 0; j < HID; ++j) hj[j] = rl(h, j);
                __builtin_amdgcn_sched_barrier(0);

                float d1a = xgr[ti].x, d2a = xgr[ti].y;
                float d1b = 0.0f, d2b = 0.0f;
#pragma unroll
                for (int j = 0; j < HID; j += 2) {
                    d1a = fmaf(hj[j],     w1[j],     d1a);
                    d2a = fmaf(hj[j],     w2[j],     d2a);
                    d1b = fmaf(hj[j + 1], w1[j + 1], d1b);
                    d2b = fmaf(hj[j + 1], w2[j + 1], d2b);
                }
                const float d1 = d1a + d1b;
                const float d2 = d2a + d2b;

                const float s1   = sig2(d1);               // sig(i) or sig(2g)
                const float act1 = fmaf(s1, aAct, cAct);   // sig(i) or tanh(g)
                const float act2 = sig2(d2);               // sig(f) or sig(o)

                const float og1 = xhalf(act1);             // low lanes: tanh(g)
                const float og2 = xhalf(act2);             // low lanes: sig(o)

                c = fmaf(act2, c, act1 * og1);             // low: f*c + i*tanh(g)
                const float tc = fmaf(2.0f, sig2(c * (2.0f * L2E)), -1.0f); // tanh(c)
                h = og2 * tc;                              // low: o * tanh(c)

                const int t = kt * TILE + ti;
                if (lane < HID) hist[(t & 63) * HID + lane] = h;
            }
        }
        __syncthreads();                           // expose last tile's hist
    } else {
        // ======================= PRODUCER (xg + output) =======================
        // (byte-identical to the round-2 passing producer)
        const int cA = lane;                       // columns 0..63
        const int cB = 64 + (lane & 15);           // columns 64..79 ('o' tail)
        const float scA = ((cA >= 40 && cA < 60) ? 2.0f : 1.0f) * L2E;
        const float scB = L2E;

        float wA[DIN], wB[DIN];
#pragma unroll
        for (int d = 0; d < DIN; ++d) {
            wA[d] = samp(wih_mu, wih_rho, wih_eps, d * G4 + cA) * scA;
            wB[d] = samp(wih_mu, wih_rho, wih_eps, d * G4 + cB) * scB;
        }
        const float biasA = samp(bmu, brho, beps, cA) * scA;
        const float biasB = samp(bmu, brho, beps, cB) * scB;

        const int posA = ((cA >= 40) ? 40 : 0) + (cA % 20) * 2 + ((cA / 20) & 1);
        const int posB = ((cB >= 40) ? 40 : 0) + (cB % 20) * 2 + ((cB / 20) & 1);
        const int qs   = (lane >> 4) * 4;          // dotB step group

        float wl[HID];
#pragma unroll
        for (int j = 0; j < HID; ++j) wl[j] = wlin[j];
        const float bl = blin[0];

        // produce tile kt into lds_xg[kt&1]
        auto produce = [&](int kt) {
            const float* xu = xrow + kt * TILE * DIN;
            float* xgb = lds_xg[kt & 1];
            // stage x tile (for dotB)
            {
                const float4* src = (const float4*)xu;
                float4 v0 = src[lane * 2 + 0];
                float4 v1 = src[lane * 2 + 1];
                ((float4*)lds_x)[lane * 2 + 0] = v0;
                ((float4*)lds_x)[lane * 2 + 1] = v1;
            }
            // dotA: uniform x (scalarizable s_loads), 16 steps, 64 columns
#pragma unroll
            for (int s = 0; s < TILE; ++s) {
                float a0 = 0.0f, a1 = 0.0f;
#pragma unroll
                for (int d = 0; d < 16; ++d) {
                    a0 = fmaf(xu[s * DIN + d],      wA[d],      a0);
                    a1 = fmaf(xu[s * DIN + d + 16], wA[d + 16], a1);
                }
                xgb[s * G4 + posA] = biasA + a0 + a1;
            }
            // dotB: 16 extra columns, 4 steps per lane, x from LDS
#pragma unroll
            for (int jj = 0; jj < 4; ++jj) {
                const int s = qs + jj;
                const float4* xr = (const float4*)&lds_x[s * DIN];
                float a0 = 0.0f, a1 = 0.0f;
#pragma unroll
                for (int q = 0; q < 4; ++q) {
                    const float4 u0 = xr[q], u1 = xr[q + 4];
                    a0 = fmaf(u0.x, wB[q * 4 + 0],      a0);
                    a0 = fmaf(u0.y, wB[q * 4 + 1],      a0);
                    a0 = fmaf(u0.z, wB[q * 4 + 2],      a0);
                    a0 = fmaf(u0.w, wB[q * 4 + 3],      a0);
                    a1 = fmaf(u1.x, wB[16 + q * 4 + 0], a1);
                    a1 = fmaf(u1.y, wB[16 + q * 4 + 1], a1);
                    a1 = fmaf(u1.z, wB[16 + q * 4 + 2], a1);
                    a1 = fmaf(u1.w, wB[16 + q * 4 + 3], a1);
                }
                xgb[s * G4 + posB] = biasB + a0 + a1;
            }
        };

        // flush outputs for tile ft (hist already complete & barrier-visible)
        auto flush = [&](int ft) {
            if (lane < TILE) {
                const int t = ft * TILE + lane;
                const float4* hr = (const float4*)&hist[(t & 63) * HID];
                const float4 r0 = hr[0], r1 = hr[1], r2 = hr[2], r3 = hr[3], r4 = hr[4];
                float acc = bl;
                acc = fmaf(r0.x, wl[0],  acc); acc = fmaf(r0.y, wl[1],  acc);
                acc = fmaf(r0.z, wl[2],  acc); acc = fmaf(r0.w, wl[3],  acc);
                acc = fmaf(r1.x, wl[4],  acc); acc = fmaf(r1.y, wl[5],  acc);
                acc = fmaf(r1.z, wl[6],  acc); acc = fmaf(r1.w, wl[7],  acc);
                acc = fmaf(r2.x, wl[8],  acc); acc = fmaf(r2.y, wl[9],  acc);
                acc = fmaf(r2.z, wl[10], acc); acc = fmaf(r2.w, wl[11], acc);
                acc = fmaf(r3.x, wl[12], acc); acc = fmaf(r3.y, wl[13], acc);
                acc = fmaf(r3.z, wl[14], acc); acc = fmaf(r3.w, wl[15], acc);
                acc = fmaf(r4.x, wl[16], acc); acc = fmaf(r4.y, wl[17], acc);
                acc = fmaf(r4.z, wl[18], acc); acc = fmaf(r4.w, wl[19], acc);
                outp[t] = acc;
            }
        };

        produce(0);
        for (int kt = 0; kt < NT; ++kt) {
            __syncthreads();                       // release tile kt
            if (kt + 1 < NT) produce(kt + 1);
            if (kt >= 1)     flush(kt - 1);
        }
        __syncthreads();                           // consumer's last tile visible
        flush(NT - 1);
    }
}

extern "C" void kernel_launch(void* const* d_in, const int* in_sizes, int n_in,
                              void* d_out, int out_size, void* d_ws, size_t ws_size,
                              hipStream_t stream) {
    const float* x       = (const float*)d_in[0];
    const float* wih_mu  = (const float*)d_in[1];
    const float* wih_rho = (const float*)d_in[2];
    const float* wih_eps = (const float*)d_in[3];
    const float* whh_mu  = (const float*)d_in[4];
    const float* whh_rho = (const float*)d_in[5];
    const float* whh_eps = (const float*)d_in[6];
    const float* bmu     = (const float*)d_in[7];
    const float* brho    = (const float*)d_in[8];
    const float* beps    = (const float*)d_in[9];
    const float* wlin    = (const float*)d_in[10];
    const float* blin    = (const float*)d_in[11];
    float* out = (float*)d_out;

    const int B = in_sizes[0] / (TSEQ * DIN);   // 256

    blstm_kernel<<<B, 128, 0, stream>>>(x, wih_mu, wih_rho, wih_eps,
                                        whh_mu, whh_rho, whh_eps,
                                        bmu, brho, beps, wlin, blin, out);
}